// Round 15
// baseline (38.605 us; speedup 1.0000x reference)
//
#include <hip/hip_runtime.h>

// RNNT (Transducer) alpha-recursion loss, forward, mean reduction.
// B=4, T=512, U=100 (U+1=101 cols), V=1024, fp32.
//
// Linear-domain DP (recurrence linear over (+,x)):
//   a[t][u] = a[t-1][u]*fB + a[t][u-1]*fE
// R15: 8-STEP FUSION (banded-operator composition of two verified 4-step
// maps, done by the WIDE gather) + balanced FMA trees in the DP.
// 8-step map (per lane; Xk = X at lane l-k):
//   A' = Paa0*A + Paa1*A1 + Paa2*A2 + Paa3*A3 + Paa4*A4
//      + Pab1*B1 + Pab2*B2 + Pab3*B3 + Pab4*B4
//   B' = Pba0*A + Pba1*A1 + Pba2*A2 + Pba3*A3
//      + Pbb0*B + Pbb1*B1 + Pbb2*B2 + Pbb3*B3 + Pbb4*B4
// Composition rule (M = first 4 rows, N = next 4; su_i = shfl_up by i):
//   P**_m = sum_i N**_i * su_i(M**_{m-i})   (2x2 block-banded convolution)
// Identity checks pass both ways; lane<i shuffle garbage is killed by
// exact-zero N coefficients (same mechanism verified in R12/R13).
// DP: 77 dependent macro-iterations (vs 153); per macro 8 chained DPP +
// balanced trees of 9 f64 terms (depth ~3) + 9 b128 loads, check-free via
// identity padding (R14). W=3 groups, mod-3 pipeline (~324 buffer VGPRs).
// Whole-macro normalization by shared rounded mean m (scale 8m). Tail
// rem=smax&7 raw steps. Two-kernel structure (overlap refuted R8/R11).

constexpr int B = 4, T = 512, U = 100, Up1 = 101, V = 1024;
constexpr int DIAGS = T + U;        // 612
constexpr int MM8 = 78;             // 8-diagonal macro rows (padded)
constexpr int W = 3;                // macro-steps per load group
constexpr float LOG2E = 1.44269504088896340736f;
constexpr float LN2 = 0.69314718055994530942f;

__device__ double2 g_G1[(size_t)B * MM8 * 64];  // {Paa0, Paa1}
__device__ double2 g_G2[(size_t)B * MM8 * 64];  // {Paa2, Paa3}
__device__ double2 g_G3[(size_t)B * MM8 * 64];  // {Paa4, Pab1}
__device__ double2 g_G4[(size_t)B * MM8 * 64];  // {Pab2, Pab3}
__device__ double2 g_G5[(size_t)B * MM8 * 64];  // {Pab4, Pba0}
__device__ double2 g_G6[(size_t)B * MM8 * 64];  // {Pba1, Pba2}
__device__ double2 g_G7[(size_t)B * MM8 * 64];  // {Pba3, Pbb0}
__device__ double2 g_G8[(size_t)B * MM8 * 64];  // {Pbb1, Pbb2}
__device__ double2 g_G9[(size_t)B * MM8 * 64];  // {Pbb3, Pbb4}
__device__ double2 g_L1[7][B * 64];             // tail raw {x,z}
__device__ double2 g_L2[7][B * 64];             // tail raw {y,w}
__device__ float g_mm[B * MM8];                 // per-macro log2 scale (=8m)
__device__ float g_lastm[B][7];                 // tail per-row scales
__device__ float g_ps[B];                       // per-sample log2(alpha)
__device__ int g_ctr = 0;

__device__ __forceinline__ int clampi(int x, int lo, int hi) {
  return x < lo ? lo : (x > hi ? hi : x);
}
__device__ __forceinline__ float fexp2(float x) {
  float r; asm("v_exp_f32 %0, %1" : "=v"(r) : "v"(x)); return r;
}
__device__ __forceinline__ float flog2(float x) {
  float r; asm("v_log_f32 %0, %1" : "=v"(r) : "v"(x)); return r;
}
// whole-wave shift by 1 on a double: lane l receives lane l-1's value
// (lane 0 keeps its own; its coefficients for shifted terms are exact 0)
__device__ __forceinline__ double wave_shr1_f64(double x) {
  int hi = __double2hiint(x), lo = __double2loint(x);
  hi = __builtin_amdgcn_update_dpp(hi, hi, 0x138 /*WF_SR1*/, 0xF, 0xF, false);
  lo = __builtin_amdgcn_update_dpp(lo, lo, 0x138 /*WF_SR1*/, 0xF, 0xF, false);
  return __hiloint2double(hi, lo);
}

__global__ __launch_bounds__(256) void gather_kernel(const float* __restrict__ logits,
                                                     const int* __restrict__ labels,
                                                     const int* __restrict__ logit_len,
                                                     const int* __restrict__ label_len) {
  const int b = blockIdx.y;
  const int mr = blockIdx.x * 4 + (threadIdx.x >> 6);   // 8-diag macro index
  const int l = threadIdx.x & 63;
  if (mr >= MM8) return;
  const int Tb = clampi(logit_len[b], 1, T);
  const int Ub = clampi(label_len[b], 1, U);
  const int smax = Tb - 1 + Ub;
  const int Mq8 = smax >> 3, rem = smax & 7;

  const float* lg = logits + (size_t)b * T * Up1 * V;
  const int u0 = 2 * l, u1 = u0 + 1;
  int labz = 0, labw = 0;
  if (u0 >= 1 && u0 <= U) labz = clampi(labels[b * U + (u0 - 1)], 0, V - 1);
  if (u0 < U)             labw = clampi(labels[b * U + u0], 0, V - 1);

  // raw (log2-scaled) components + validity of one diagonal row r
#define RAWROW(r, vx, vy, vz, vw, bx, by, bz, bw)                              \
  {                                                                            \
    vx = vy = vz = vw = 0.f; bx = by = bz = bw = false;                        \
    int tx = (r) - u0;                                                         \
    if (u0 <= Ub && tx >= 0 && tx <= Tb - 1) { vx = LOG2E * lg[((size_t)tx * Up1 + u0) * V]; bx = true; } \
    int ty = (r) - u1;                                                         \
    if (u1 <= Ub && ty >= 0 && ty <= Tb - 1) { vy = LOG2E * lg[((size_t)ty * Up1 + u1) * V]; by = true; } \
    int tz = (r) - u0 + 1;                                                     \
    if (u0 >= 1 && u0 <= Ub && tz >= 0 && tz <= Tb - 1) { vz = LOG2E * lg[((size_t)tz * Up1 + (u0 - 1)) * V + labz]; bz = true; } \
    int tw = (r) - u0;                                                         \
    if (u0 <= Ub - 1 && tw >= 0 && tw <= Tb - 1) { vw = LOG2E * lg[((size_t)tw * Up1 + u0) * V + labw]; bw = true; } \
  }

  if (mr >= Mq8) {
    // identity macro (numeric no-op) -> DP runs check-free full groups
    const size_t idx = ((size_t)b * MM8 + mr) * 64 + l;
    g_G1[idx] = make_double2(1.0, 0.0);
    g_G2[idx] = make_double2(0.0, 0.0);
    g_G3[idx] = make_double2(0.0, 0.0);
    g_G4[idx] = make_double2(0.0, 0.0);
    g_G5[idx] = make_double2(0.0, 0.0);
    g_G6[idx] = make_double2(0.0, 0.0);
    g_G7[idx] = make_double2(0.0, 1.0);
    g_G8[idx] = make_double2(0.0, 0.0);
    g_G9[idx] = make_double2(0.0, 0.0);
    if (l == 0) g_mm[b * MM8 + mr] = 0.f;

    if (mr == Mq8) {                    // tail rows 8*Mq8+j, j<rem
      for (int j = 0; j < rem; ++j) {
        int r = 8 * Mq8 + j;
        float vx, vy, vz, vw; bool bx, by, bz, bw;
        RAWROW(r, vx, vy, vz, vw, bx, by, bz, bw);
        float s_ = (bx ? vx : 0.f) + (by ? vy : 0.f) + (bz ? vz : 0.f) + (bw ? vw : 0.f);
        float c_ = (float)((int)bx + (int)by + (int)bz + (int)bw);
        for (int off = 32; off; off >>= 1) { s_ += __shfl_xor(s_, off, 64); c_ += __shfl_xor(c_, off, 64); }
        float m = (c_ > 0.f) ? rintf(s_ / c_) : 0.f;
        g_L1[j][b * 64 + l] = make_double2(bx ? (double)fexp2(vx - m) : 0.0,
                                           bz ? (double)fexp2(vz - m) : 0.0);
        g_L2[j][b * 64 + l] = make_double2(by ? (double)fexp2(vy - m) : 0.0,
                                           bw ? (double)fexp2(vw - m) : 0.0);
        if (l == 0) g_lastm[b][j] = m;
      }
    }
    return;
  }

  // ---- full macro: rows 8mr .. 8mr+7 ----
  float vx[8], vy[8], vz[8], vw[8];
  bool bx[8], by[8], bz[8], bw[8];
#pragma unroll
  for (int k = 0; k < 8; ++k)
    RAWROW(8 * mr + k, vx[k], vy[k], vz[k], vw[k], bx[k], by[k], bz[k], bw[k]);

  // shared rounded-mean normalization over the whole macro (8 rows)
  float s_ = 0.f, c_ = 0.f;
#pragma unroll
  for (int k = 0; k < 8; ++k) {
    s_ += (bx[k] ? vx[k] : 0.f) + (by[k] ? vy[k] : 0.f) +
          (bz[k] ? vz[k] : 0.f) + (bw[k] ? vw[k] : 0.f);
    c_ += (float)((int)bx[k] + (int)by[k] + (int)bz[k] + (int)bw[k]);
  }
  for (int off = 32; off; off >>= 1) { s_ += __shfl_xor(s_, off, 64); c_ += __shfl_xor(c_, off, 64); }
  const float m = (c_ > 0.f) ? rintf(s_ / c_) : 0.f;

  float fX[8], fY[8], fZ[8], fW[8];
#pragma unroll
  for (int k = 0; k < 8; ++k) {
    fX[k] = bx[k] ? fexp2(vx[k] - m) : 0.f;
    fY[k] = by[k] ? fexp2(vy[k] - m) : 0.f;
    fZ[k] = bz[k] ? fexp2(vz[k] - m) : 0.f;
    fW[k] = bw[k] ? fexp2(vw[k] - m) : 0.f;
  }

  // 2-step composition (R12-verified): rows i (first) then jj (second)
#define COMP2(P, Q, R_, S, Tc, Uc, i, jj)                                      \
  {                                                                            \
    float y1n = __shfl_up(fY[i], 1, 64);                                       \
    float w1n = __shfl_up(fW[i], 1, 64);                                       \
    double X1 = fX[i], Y1 = fY[i], Z1 = fZ[i], W1 = fW[i];                     \
    double X2 = fX[jj], Y2 = fY[jj], Z2 = fZ[jj], W2 = fW[jj];                 \
    P = X2 * X1; Q = X2 * Z1 + Z2 * (double)y1n; R_ = Z2 * (double)w1n;        \
    S = Y2 * Y1; Tc = W2 * X1 + Y2 * W1; Uc = W2 * Z1;                         \
  }
  // 4-step banded map from rows i0..i0+3 (R13-verified composition):
  // aa0,aa1,aa2, ab1,ab2, ba0,ba1, bb0,bb1,bb2
#define COMP4(aa0, aa1, aa2, ab1, ab2, ba0, ba1, bb0, bb1, bb2, i0)            \
  {                                                                            \
    double Mp, Mq_, Mr, Ms, Mt, Mu, Np, Nq, Nr, Ns, Nt, Nu;                    \
    COMP2(Mp, Mq_, Mr, Ms, Mt, Mu, (i0), (i0) + 1);                            \
    COMP2(Np, Nq, Nr, Ns, Nt, Nu, (i0) + 2, (i0) + 3);                         \
    double Mp1 = __shfl_up(Mp, 1, 64), Mq1 = __shfl_up(Mq_, 1, 64);            \
    double Mr1 = __shfl_up(Mr, 1, 64), Ms1 = __shfl_up(Ms, 1, 64);             \
    double Mt1 = __shfl_up(Mt, 1, 64), Mu1 = __shfl_up(Mu, 1, 64);             \
    aa0 = Np * Mp;                                                             \
    ab1 = Np * Mq_ + Nq * Ms1;                                                 \
    aa1 = Np * Mr + Nq * Mt1 + Nr * Mp1;                                       \
    ab2 = Nq * Mu1 + Nr * Mq1;                                                 \
    aa2 = Nr * Mr1;                                                            \
    bb0 = Ns * Ms;                                                             \
    ba0 = Ns * Mt + Nt * Mp;                                                   \
    bb1 = Ns * Mu + Nt * Mq_ + Nu * Ms1;                                       \
    ba1 = Nt * Mr + Nu * Mt1;                                                  \
    bb2 = Nu * Mu1;                                                            \
  }

  double Maa0, Maa1, Maa2, Mab1, Mab2, Mba0, Mba1, Mbb0, Mbb1, Mbb2;
  double Naa0, Naa1, Naa2, Nab1, Nab2, Nba0, Nba1, Nbb0, Nbb1, Nbb2;
  COMP4(Maa0, Maa1, Maa2, Mab1, Mab2, Mba0, Mba1, Mbb0, Mbb1, Mbb2, 0);
  COMP4(Naa0, Naa1, Naa2, Nab1, Nab2, Nba0, Nba1, Nbb0, Nbb1, Nbb2, 4);
#undef COMP4
#undef COMP2

  // shifted copies of M's coefficients (su_i; lane<i garbage is multiplied
  // by exact-zero N coefficients)
  double sMaa0_1 = __shfl_up(Maa0, 1, 64), sMaa0_2 = __shfl_up(Maa0, 2, 64);
  double sMaa1_1 = __shfl_up(Maa1, 1, 64), sMaa1_2 = __shfl_up(Maa1, 2, 64);
  double sMaa2_1 = __shfl_up(Maa2, 1, 64), sMaa2_2 = __shfl_up(Maa2, 2, 64);
  double sMab1_1 = __shfl_up(Mab1, 1, 64), sMab1_2 = __shfl_up(Mab1, 2, 64);
  double sMab2_1 = __shfl_up(Mab2, 1, 64), sMab2_2 = __shfl_up(Mab2, 2, 64);
  double sMba0_1 = __shfl_up(Mba0, 1, 64), sMba0_2 = __shfl_up(Mba0, 2, 64);
  double sMba1_1 = __shfl_up(Mba1, 1, 64), sMba1_2 = __shfl_up(Mba1, 2, 64);
  double sMbb0_1 = __shfl_up(Mbb0, 1, 64), sMbb0_2 = __shfl_up(Mbb0, 2, 64);
  double sMbb1_1 = __shfl_up(Mbb1, 1, 64), sMbb1_2 = __shfl_up(Mbb1, 2, 64);
  double sMbb2_1 = __shfl_up(Mbb2, 1, 64), sMbb2_2 = __shfl_up(Mbb2, 2, 64);

  // 8-step composition P = N o M (2x2 block-banded convolution)
  double Paa0 = Naa0 * Maa0;
  double Paa1 = Naa0 * Maa1 + Naa1 * sMaa0_1 + Nab1 * sMba0_1;
  double Paa2 = Naa0 * Maa2 + Naa1 * sMaa1_1 + Naa2 * sMaa0_2 +
                Nab1 * sMba1_1 + Nab2 * sMba0_2;
  double Paa3 = Naa1 * sMaa2_1 + Naa2 * sMaa1_2 + Nab2 * sMba1_2;
  double Paa4 = Naa2 * sMaa2_2;
  double Pab1 = Naa0 * Mab1 + Nab1 * sMbb0_1;
  double Pab2 = Naa0 * Mab2 + Naa1 * sMab1_1 + Nab1 * sMbb1_1 + Nab2 * sMbb0_2;
  double Pab3 = Naa1 * sMab2_1 + Naa2 * sMab1_2 + Nab1 * sMbb2_1 + Nab2 * sMbb1_2;
  double Pab4 = Naa2 * sMab2_2 + Nab2 * sMbb2_2;
  double Pba0 = Nba0 * Maa0 + Nbb0 * Mba0;
  double Pba1 = Nba0 * Maa1 + Nba1 * sMaa0_1 + Nbb0 * Mba1 + Nbb1 * sMba0_1;
  double Pba2 = Nba0 * Maa2 + Nba1 * sMaa1_1 + Nbb1 * sMba1_1 + Nbb2 * sMba0_2;
  double Pba3 = Nba1 * sMaa2_1 + Nbb2 * sMba1_2;
  double Pbb0 = Nbb0 * Mbb0;
  double Pbb1 = Nba0 * Mab1 + Nbb0 * Mbb1 + Nbb1 * sMbb0_1;
  double Pbb2 = Nba0 * Mab2 + Nba1 * sMab1_1 + Nbb0 * Mbb2 + Nbb1 * sMbb1_1 +
                Nbb2 * sMbb0_2;
  double Pbb3 = Nba1 * sMab2_1 + Nbb1 * sMbb2_1 + Nbb2 * sMbb1_2;
  double Pbb4 = Nbb2 * sMbb2_2;

  const size_t idx = ((size_t)b * MM8 + mr) * 64 + l;
  g_G1[idx] = make_double2(Paa0, Paa1);
  g_G2[idx] = make_double2(Paa2, Paa3);
  g_G3[idx] = make_double2(Paa4, Pab1);
  g_G4[idx] = make_double2(Pab2, Pab3);
  g_G5[idx] = make_double2(Pab4, Pba0);
  g_G6[idx] = make_double2(Pba1, Pba2);
  g_G7[idx] = make_double2(Pba3, Pbb0);
  g_G8[idx] = make_double2(Pbb1, Pbb2);
  g_G9[idx] = make_double2(Pbb3, Pbb4);
  if (l == 0) g_mm[b * MM8 + mr] = 8.f * m;
#undef RAWROW
}

__global__ __launch_bounds__(64, 1)
void dp_kernel(const int* __restrict__ logit_len,
               const int* __restrict__ label_len,
               float* __restrict__ out) {
  const int b = blockIdx.x;
  const int lane = threadIdx.x;
  const int Tb = clampi(logit_len[b], 1, T);
  const int Ub = clampi(label_len[b], 1, U);
  const int smax = Tb - 1 + Ub;
  const int Mq8 = smax >> 3, rem = smax & 7;
  const double2* G1 = g_G1 + (size_t)b * MM8 * 64 + lane;
  const double2* G2 = g_G2 + (size_t)b * MM8 * 64 + lane;
  const double2* G3 = g_G3 + (size_t)b * MM8 * 64 + lane;
  const double2* G4 = g_G4 + (size_t)b * MM8 * 64 + lane;
  const double2* G5 = g_G5 + (size_t)b * MM8 * 64 + lane;
  const double2* G6 = g_G6 + (size_t)b * MM8 * 64 + lane;
  const double2* G7 = g_G7 + (size_t)b * MM8 * 64 + lane;
  const double2* G8 = g_G8 + (size_t)b * MM8 * 64 + lane;
  const double2* G9 = g_G9 + (size_t)b * MM8 * 64 + lane;

  double A = (lane == 0) ? 1.0 : 0.0;   // alpha[0][0] = 1 (diag 0 done)
  double Bc = 0.0;

  double2 a1[W], a2[W], a3[W], a4[W], a5[W], a6[W], a7[W], a8[W], a9[W];
  double2 b1[W], b2[W], b3[W], b4[W], b5[W], b6[W], b7[W], b8[W], b9[W];
  double2 c1[W], c2[W], c3[W], c4[W], c5[W], c6[W], c7[W], c8[W], c9[W];

#define LOADG(u1_, u2_, u3_, u4_, u5_, u6_, u7_, u8_, u9_, grp)                \
  {                                                                            \
    const size_t o_ = (size_t)(grp) * (W * 64);                                \
    _Pragma("unroll")                                                          \
    for (int j_ = 0; j_ < W; ++j_) {                                           \
      u1_[j_] = G1[o_ + j_ * 64]; u2_[j_] = G2[o_ + j_ * 64];                  \
      u3_[j_] = G3[o_ + j_ * 64]; u4_[j_] = G4[o_ + j_ * 64];                  \
      u5_[j_] = G5[o_ + j_ * 64]; u6_[j_] = G6[o_ + j_ * 64];                  \
      u7_[j_] = G7[o_ + j_ * 64]; u8_[j_] = G8[o_ + j_ * 64];                  \
      u9_[j_] = G9[o_ + j_ * 64];                                              \
    }                                                                          \
  }

  // balanced trees (depth ~3) over the 9-term updates
#define STEPS(u1_, u2_, u3_, u4_, u5_, u6_, u7_, u8_, u9_)                     \
  {                                                                            \
    _Pragma("unroll")                                                          \
    for (int j_ = 0; j_ < W; ++j_) {                                           \
      double A1s = wave_shr1_f64(A);                                           \
      double B1s = wave_shr1_f64(Bc);                                          \
      double A2s = wave_shr1_f64(A1s);                                         \
      double B2s = wave_shr1_f64(B1s);                                         \
      double A3s = wave_shr1_f64(A2s);                                         \
      double B3s = wave_shr1_f64(B2s);                                         \
      double A4s = wave_shr1_f64(A3s);                                         \
      double B4s = wave_shr1_f64(B3s);                                         \
      double na = ((A * u1_[j_].x + A1s * u1_[j_].y) +                         \
                   (A2s * u2_[j_].x + A3s * u2_[j_].y)) +                      \
                  ((A4s * u3_[j_].x + B1s * u3_[j_].y) +                       \
                   (B2s * u4_[j_].x + B3s * u4_[j_].y)) +                      \
                  B4s * u5_[j_].x;                                             \
      double nb = ((A * u5_[j_].y + A1s * u6_[j_].x) +                         \
                   (A2s * u6_[j_].y + A3s * u7_[j_].x)) +                      \
                  ((Bc * u7_[j_].y + B1s * u8_[j_].x) +                        \
                   (B2s * u8_[j_].y + B3s * u9_[j_].x)) +                      \
                  B4s * u9_[j_].y;                                             \
      A = na; Bc = nb;                                                         \
    }                                                                          \
  }

  const int NWC = (Mq8 + W - 1) / W;    // full groups (identity-padded)
  if (NWC > 0) {
    LOADG(a1, a2, a3, a4, a5, a6, a7, a8, a9, 0);
    if (NWC > 1) LOADG(b1, b2, b3, b4, b5, b6, b7, b8, b9, 1);
    for (int k = 0; k < NWC; k += 3) {
      if (k + 2 < NWC) LOADG(c1, c2, c3, c4, c5, c6, c7, c8, c9, k + 2);
      STEPS(a1, a2, a3, a4, a5, a6, a7, a8, a9);
      if (k + 1 < NWC) {
        if (k + 3 < NWC) LOADG(a1, a2, a3, a4, a5, a6, a7, a8, a9, k + 3);
        STEPS(b1, b2, b3, b4, b5, b6, b7, b8, b9);
        if (k + 2 < NWC) {
          if (k + 4 < NWC) LOADG(b1, b2, b3, b4, b5, b6, b7, b8, b9, k + 4);
          STEPS(c1, c2, c3, c4, c5, c6, c7, c8, c9);
        }
      }
    }
  }
  // tail: rem raw single steps (rows 8*Mq8 .. smax-1)
  for (int j = 0; j < rem; ++j) {
    double2 L1 = g_L1[j][b * 64 + lane];      // {x, z}
    double2 L2 = g_L2[j][b * 64 + lane];      // {y, w}
    double shrB = wave_shr1_f64(Bc);
    double na = fma(A, L1.x, shrB * L1.y);
    double nb = fma(Bc, L2.x, A * L2.y);
    A = na; Bc = nb;
  }

  // answer cell (Tb-1, Ub) produced at step smax
  const int ansLane = Ub >> 1;
  double va = __shfl(A, ansLane, 64);
  double vb = __shfl(Bc, ansLane, 64);
  double v = (Ub & 1) ? vb : va;
  int ev = ((__double2hiint(v) >> 20) & 0x7ff) - 1023;
  double mant = ldexp(v, -ev);

  float msum = 0.f;
  for (int mI = lane; mI < Mq8; mI += 64) msum += g_mm[b * MM8 + mI];
  for (int off = 32; off; off >>= 1) msum += __shfl_xor(msum, off, 64);
  for (int j = 0; j < rem; ++j) msum += g_lastm[b][j];

  float lg2 = (float)ev + flog2((float)mant) + msum;

  if (lane == 0) {
    __hip_atomic_store(&g_ps[b], lg2, __ATOMIC_RELEASE, __HIP_MEMORY_SCOPE_AGENT);
    int old = __hip_atomic_fetch_add(&g_ctr, 1, __ATOMIC_ACQ_REL,
                                     __HIP_MEMORY_SCOPE_AGENT);
    if (old == B - 1) {
      float s = 0.0f;
      for (int i = 0; i < B; ++i)
        s += __hip_atomic_load(&g_ps[i], __ATOMIC_ACQUIRE, __HIP_MEMORY_SCOPE_AGENT);
      out[0] = -s * (LN2 / B);
      __hip_atomic_store(&g_ctr, 0, __ATOMIC_RELAXED, __HIP_MEMORY_SCOPE_AGENT);
    }
  }
#undef LOADG
#undef STEPS
}

extern "C" void kernel_launch(void* const* d_in, const int* in_sizes, int n_in,
                              void* d_out, int out_size, void* d_ws, size_t ws_size,
                              hipStream_t stream) {
  const float* logits = (const float*)d_in[0];
  const int* labels = (const int*)d_in[1];
  const int* logit_len = (const int*)d_in[2];
  const int* label_len = (const int*)d_in[3];
  float* out = (float*)d_out;

  hipLaunchKernelGGL(gather_kernel, dim3((MM8 + 3) / 4, B), dim3(256), 0, stream,
                     logits, labels, logit_len, label_len);
  hipLaunchKernelGGL(dp_kernel, dim3(B), dim3(64), 0, stream,
                     logit_len, label_len, out);
}

// Round 16
// 30.698 us; speedup vs baseline: 1.2576x; 1.2576x over previous
//
#include <hip/hip_runtime.h>

// RNNT (Transducer) alpha-recursion loss, forward, mean reduction.
// B=4, T=512, U=100 (U+1=101 cols), V=1024, fp32.
//
// Linear-domain DP (recurrence linear over (+,x)):
//   a[t][u] = a[t-1][u]*fB + a[t][u-1]*fE
// R16 = R14 (4-step fusion, check-free identity-padded inner loop) with
// W=4 -> 5: prefetch lookahead 2*W*66 = 528 -> 660 cy, covering the ~600cy
// remote-L2/L3 latency of the staged coefficient reads. (R15's 8-step
// fusion failed exactly here: fewer issue cycles per group shrank the
// mod-3 pipeline's lookahead TIME to ~212cy -> every group stalled.)
// 4-step map (per lane, Xk = value at lane l-k):
//   A'' = dA*A + dB1*B1 + dA1*A1 + dB2*B2 + dA2*A2
//   B'' = eB*B + eA*A + eB1*B1 + eA1*A1 + eB2*B2
// composed in the WIDE gather from two verified 2-step maps (R12).
// Whole-macro normalization by shared rounded mean m; scales summed
// post-loop. Tail rem=smax&3 raw steps. Two-kernel structure (overlap
// refuted R8/R11). MM4 padded to NWC_max*W = 31*5 = 155 identity macros.

constexpr int B = 4, T = 512, U = 100, Up1 = 101, V = 1024;
constexpr int DIAGS = T + U;        // 612
constexpr int MM4 = 155;            // macro rows, padded to ceil(152/5)*5
constexpr int W = 5;                // macro-steps per load group (mod-3 pipe)
constexpr float LOG2E = 1.44269504088896340736f;
constexpr float LN2 = 0.69314718055994530942f;

__device__ double2 g_D1[(size_t)B * MM4 * 64];  // {dA,  dB1}
__device__ double2 g_D2[(size_t)B * MM4 * 64];  // {dA1, dB2}
__device__ double2 g_D3[(size_t)B * MM4 * 64];  // {dA2, eB }
__device__ double2 g_D4[(size_t)B * MM4 * 64];  // {eA,  eB1}
__device__ double2 g_D5[(size_t)B * MM4 * 64];  // {eA1, eB2}
__device__ double2 g_L1[3][B * 64];             // tail raw {x,z}
__device__ double2 g_L2[3][B * 64];             // tail raw {y,w}
__device__ float g_mm[B * MM4];                 // per-macro log2 scale (=4m)
__device__ float g_lastm[B][3];                 // tail per-row scales
__device__ float g_ps[B];                       // per-sample log2(alpha)
__device__ int g_ctr = 0;

__device__ __forceinline__ int clampi(int x, int lo, int hi) {
  return x < lo ? lo : (x > hi ? hi : x);
}
__device__ __forceinline__ float fexp2(float x) {
  float r; asm("v_exp_f32 %0, %1" : "=v"(r) : "v"(x)); return r;
}
__device__ __forceinline__ float flog2(float x) {
  float r; asm("v_log_f32 %0, %1" : "=v"(r) : "v"(x)); return r;
}
// whole-wave shift by 1 on a double: lane l receives lane l-1's value
// (lane 0 keeps its own; its coefficients for shifted terms are exact 0)
__device__ __forceinline__ double wave_shr1_f64(double x) {
  int hi = __double2hiint(x), lo = __double2loint(x);
  hi = __builtin_amdgcn_update_dpp(hi, hi, 0x138 /*WF_SR1*/, 0xF, 0xF, false);
  lo = __builtin_amdgcn_update_dpp(lo, lo, 0x138 /*WF_SR1*/, 0xF, 0xF, false);
  return __hiloint2double(hi, lo);
}

__global__ __launch_bounds__(256) void gather_kernel(const float* __restrict__ logits,
                                                     const int* __restrict__ labels,
                                                     const int* __restrict__ logit_len,
                                                     const int* __restrict__ label_len) {
  const int b = blockIdx.y;
  const int mr = blockIdx.x * 4 + (threadIdx.x >> 6);   // macro row index
  const int l = threadIdx.x & 63;
  if (mr >= MM4) return;
  const int Tb = clampi(logit_len[b], 1, T);
  const int Ub = clampi(label_len[b], 1, U);
  const int smax = Tb - 1 + Ub;
  const int Mq = smax >> 2, rem = smax & 3;

  const float* lg = logits + (size_t)b * T * Up1 * V;
  const int u0 = 2 * l, u1 = u0 + 1;
  int labz = 0, labw = 0;
  if (u0 >= 1 && u0 <= U) labz = clampi(labels[b * U + (u0 - 1)], 0, V - 1);
  if (u0 < U)             labw = clampi(labels[b * U + u0], 0, V - 1);

  if (mr >= Mq) {
    // identity macro (numeric no-op) so the DP can run check-free groups
    const size_t idx = ((size_t)b * MM4 + mr) * 64 + l;
    g_D1[idx] = make_double2(1.0, 0.0);
    g_D2[idx] = make_double2(0.0, 0.0);
    g_D3[idx] = make_double2(0.0, 1.0);
    g_D4[idx] = make_double2(0.0, 0.0);
    g_D5[idx] = make_double2(0.0, 0.0);
    if (l == 0) g_mm[b * MM4 + mr] = 0.f;

    if (mr == Mq) {                     // tail rows 4Mq+j, j<rem (raw factors)
      for (int j = 0; j < rem; ++j) {
        int r = 4 * Mq + j;
        float vx = 0.f, vy = 0.f, vz = 0.f, vw = 0.f;
        bool bx = false, by = false, bz = false, bw = false;
        int tx = r - u0;
        if (u0 <= Ub && tx >= 0 && tx <= Tb - 1) { vx = LOG2E * lg[((size_t)tx * Up1 + u0) * V]; bx = true; }
        int ty = r - u1;
        if (u1 <= Ub && ty >= 0 && ty <= Tb - 1) { vy = LOG2E * lg[((size_t)ty * Up1 + u1) * V]; by = true; }
        int tz = r - u0 + 1;
        if (u0 >= 1 && u0 <= Ub && tz >= 0 && tz <= Tb - 1) { vz = LOG2E * lg[((size_t)tz * Up1 + (u0 - 1)) * V + labz]; bz = true; }
        int tw = r - u0;
        if (u0 <= Ub - 1 && tw >= 0 && tw <= Tb - 1) { vw = LOG2E * lg[((size_t)tw * Up1 + u0) * V + labw]; bw = true; }
        float s_ = (bx ? vx : 0.f) + (by ? vy : 0.f) + (bz ? vz : 0.f) + (bw ? vw : 0.f);
        float c_ = (float)((int)bx + (int)by + (int)bz + (int)bw);
        for (int off = 32; off; off >>= 1) { s_ += __shfl_xor(s_, off, 64); c_ += __shfl_xor(c_, off, 64); }
        float m = (c_ > 0.f) ? rintf(s_ / c_) : 0.f;
        g_L1[j][b * 64 + l] = make_double2(bx ? (double)fexp2(vx - m) : 0.0,
                                           bz ? (double)fexp2(vz - m) : 0.0);
        g_L2[j][b * 64 + l] = make_double2(by ? (double)fexp2(vy - m) : 0.0,
                                           bw ? (double)fexp2(vw - m) : 0.0);
        if (l == 0) g_lastm[b][j] = m;
      }
    }
    return;
  }

  // ---- full macro: rows 4mr .. 4mr+3 ----
  float vx[4], vy[4], vz[4], vw[4];
  bool bx[4], by[4], bz[4], bw[4];
#pragma unroll
  for (int k = 0; k < 4; ++k) {
    int r = 4 * mr + k;
    vx[k] = vy[k] = vz[k] = vw[k] = 0.f;
    bx[k] = by[k] = bz[k] = bw[k] = false;
    int tx = r - u0;
    if (u0 <= Ub && tx >= 0 && tx <= Tb - 1) { vx[k] = LOG2E * lg[((size_t)tx * Up1 + u0) * V]; bx[k] = true; }
    int ty = r - u1;
    if (u1 <= Ub && ty >= 0 && ty <= Tb - 1) { vy[k] = LOG2E * lg[((size_t)ty * Up1 + u1) * V]; by[k] = true; }
    int tz = r - u0 + 1;
    if (u0 >= 1 && u0 <= Ub && tz >= 0 && tz <= Tb - 1) { vz[k] = LOG2E * lg[((size_t)tz * Up1 + (u0 - 1)) * V + labz]; bz[k] = true; }
    int tw = r - u0;
    if (u0 <= Ub - 1 && tw >= 0 && tw <= Tb - 1) { vw[k] = LOG2E * lg[((size_t)tw * Up1 + u0) * V + labw]; bw[k] = true; }
  }
  // shared rounded-mean normalization over the whole macro (4 rows)
  float s_ = 0.f, c_ = 0.f;
#pragma unroll
  for (int k = 0; k < 4; ++k) {
    s_ += (bx[k] ? vx[k] : 0.f) + (by[k] ? vy[k] : 0.f) +
          (bz[k] ? vz[k] : 0.f) + (bw[k] ? vw[k] : 0.f);
    c_ += (float)((int)bx[k] + (int)by[k] + (int)bz[k] + (int)bw[k]);
  }
  for (int off = 32; off; off >>= 1) { s_ += __shfl_xor(s_, off, 64); c_ += __shfl_xor(c_, off, 64); }
  const float m = (c_ > 0.f) ? rintf(s_ / c_) : 0.f;

  float fX[4], fY[4], fZ[4], fW[4];
#pragma unroll
  for (int k = 0; k < 4; ++k) {
    fX[k] = bx[k] ? fexp2(vx[k] - m) : 0.f;
    fY[k] = by[k] ? fexp2(vy[k] - m) : 0.f;
    fZ[k] = bz[k] ? fexp2(vz[k] - m) : 0.f;
    fW[k] = bw[k] ? fexp2(vw[k] - m) : 0.f;
  }

  // 2-step composition (R12-verified): rows i (first) then jj (second)
#define COMP2(P, Q, R_, S, Tc, Uc, i, jj)                                      \
  {                                                                            \
    float y1n = __shfl_up(fY[i], 1, 64);                                       \
    float w1n = __shfl_up(fW[i], 1, 64);                                       \
    double X1 = fX[i], Y1 = fY[i], Z1 = fZ[i], W1 = fW[i];                     \
    double X2 = fX[jj], Y2 = fY[jj], Z2 = fZ[jj], W2 = fW[jj];                 \
    P = X2 * X1; Q = X2 * Z1 + Z2 * (double)y1n; R_ = Z2 * (double)w1n;        \
    S = Y2 * Y1; Tc = W2 * X1 + Y2 * W1; Uc = W2 * Z1;                         \
  }
  double Mp, Mq_, Mr, Ms, Mt, Mu, Np, Nq, Nr, Ns, Nt, Nu;
  COMP2(Mp, Mq_, Mr, Ms, Mt, Mu, 0, 1);
  COMP2(Np, Nq, Nr, Ns, Nt, Nu, 2, 3);
#undef COMP2
  double Mp1 = __shfl_up(Mp, 1, 64), Mq1 = __shfl_up(Mq_, 1, 64);
  double Mr1 = __shfl_up(Mr, 1, 64), Ms1 = __shfl_up(Ms, 1, 64);
  double Mt1 = __shfl_up(Mt, 1, 64), Mu1 = __shfl_up(Mu, 1, 64);

  double dA  = Np * Mp;
  double dB1 = Np * Mq_ + Nq * Ms1;
  double dA1 = Np * Mr + Nq * Mt1 + Nr * Mp1;
  double dB2 = Nq * Mu1 + Nr * Mq1;
  double dA2 = Nr * Mr1;
  double eB  = Ns * Ms;
  double eA  = Ns * Mt + Nt * Mp;
  double eB1 = Ns * Mu + Nt * Mq_ + Nu * Ms1;
  double eA1 = Nt * Mr + Nu * Mt1;
  double eB2 = Nu * Mu1;

  const size_t idx = ((size_t)b * MM4 + mr) * 64 + l;
  g_D1[idx] = make_double2(dA, dB1);
  g_D2[idx] = make_double2(dA1, dB2);
  g_D3[idx] = make_double2(dA2, eB);
  g_D4[idx] = make_double2(eA, eB1);
  g_D5[idx] = make_double2(eA1, eB2);
  if (l == 0) g_mm[b * MM4 + mr] = 4.f * m;
}

__global__ __launch_bounds__(64, 1)
void dp_kernel(const int* __restrict__ logit_len,
               const int* __restrict__ label_len,
               float* __restrict__ out) {
  const int b = blockIdx.x;
  const int lane = threadIdx.x;
  const int Tb = clampi(logit_len[b], 1, T);
  const int Ub = clampi(label_len[b], 1, U);
  const int smax = Tb - 1 + Ub;
  const int Mq = smax >> 2, rem = smax & 3;
  // per-lane base pointers; group loads use compile-time offsets j*64
  const double2* D1 = g_D1 + (size_t)b * MM4 * 64 + lane;
  const double2* D2 = g_D2 + (size_t)b * MM4 * 64 + lane;
  const double2* D3 = g_D3 + (size_t)b * MM4 * 64 + lane;
  const double2* D4 = g_D4 + (size_t)b * MM4 * 64 + lane;
  const double2* D5 = g_D5 + (size_t)b * MM4 * 64 + lane;

  double A = (lane == 0) ? 1.0 : 0.0;   // alpha[0][0] = 1 (diag 0 done)
  double Bc = 0.0;

  double2 a1[W], a2[W], a3[W], a4[W], a5[W];
  double2 b1[W], b2[W], b3[W], b4[W], b5[W];
  double2 c1[W], c2[W], c3[W], c4[W], c5[W];

  // group grp covers macros grp*W .. grp*W+W-1; all indices < MM4 by
  // construction (NWC*W <= 155) and padded macros are identity.
#define LOADG(u1_, u2_, u3_, u4_, u5_, grp)                                    \
  {                                                                            \
    const size_t o_ = (size_t)(grp) * (W * 64);                                \
    _Pragma("unroll")                                                          \
    for (int j_ = 0; j_ < W; ++j_) {                                           \
      u1_[j_] = D1[o_ + j_ * 64];                                              \
      u2_[j_] = D2[o_ + j_ * 64];                                              \
      u3_[j_] = D3[o_ + j_ * 64];                                              \
      u4_[j_] = D4[o_ + j_ * 64];                                              \
      u5_[j_] = D5[o_ + j_ * 64];                                              \
    }                                                                          \
  }

#define STEPS(u1_, u2_, u3_, u4_, u5_)                                         \
  {                                                                            \
    _Pragma("unroll")                                                          \
    for (int j_ = 0; j_ < W; ++j_) {                                           \
      double A1s = wave_shr1_f64(A);                                           \
      double B1s = wave_shr1_f64(Bc);                                          \
      double A2s = wave_shr1_f64(A1s);                                         \
      double B2s = wave_shr1_f64(B1s);                                         \
      double na = fma(A, u1_[j_].x, fma(B1s, u1_[j_].y,                        \
                   fma(A1s, u2_[j_].x, fma(B2s, u2_[j_].y,                     \
                       A2s * u3_[j_].x))));                                    \
      double nb = fma(Bc, u3_[j_].y, fma(A, u4_[j_].x,                         \
                   fma(B1s, u4_[j_].y, fma(A1s, u5_[j_].x,                     \
                       B2s * u5_[j_].y))));                                    \
      A = na; Bc = nb;                                                         \
    }                                                                          \
  }

  const int NWC = (Mq + W - 1) / W;     // full groups (identity-padded)
  if (NWC > 0) {
    LOADG(a1, a2, a3, a4, a5, 0);
    if (NWC > 1) LOADG(b1, b2, b3, b4, b5, 1);
    for (int k = 0; k < NWC; k += 3) {
      if (k + 2 < NWC) LOADG(c1, c2, c3, c4, c5, k + 2);
      STEPS(a1, a2, a3, a4, a5);
      if (k + 1 < NWC) {
        if (k + 3 < NWC) LOADG(a1, a2, a3, a4, a5, k + 3);
        STEPS(b1, b2, b3, b4, b5);
        if (k + 2 < NWC) {
          if (k + 4 < NWC) LOADG(b1, b2, b3, b4, b5, k + 4);
          STEPS(c1, c2, c3, c4, c5);
        }
      }
    }
  }
  // tail: rem raw single steps (rows 4Mq .. smax-1)
  for (int j = 0; j < rem; ++j) {
    double2 L1 = g_L1[j][b * 64 + lane];      // {x, z}
    double2 L2 = g_L2[j][b * 64 + lane];      // {y, w}
    double shrB = wave_shr1_f64(Bc);
    double na = fma(A, L1.x, shrB * L1.y);
    double nb = fma(Bc, L2.x, A * L2.y);
    A = na; Bc = nb;
  }

  // answer cell (Tb-1, Ub) produced at step smax
  const int ansLane = Ub >> 1;
  double va = __shfl(A, ansLane, 64);
  double vb = __shfl(Bc, ansLane, 64);
  double v = (Ub & 1) ? vb : va;
  int ev = ((__double2hiint(v) >> 20) & 0x7ff) - 1023;
  double mant = ldexp(v, -ev);

  float msum = 0.f;
  for (int mI = lane; mI < Mq; mI += 64) msum += g_mm[b * MM4 + mI];
  for (int off = 32; off; off >>= 1) msum += __shfl_xor(msum, off, 64);
  for (int j = 0; j < rem; ++j) msum += g_lastm[b][j];

  float lg2 = (float)ev + flog2((float)mant) + msum;

  if (lane == 0) {
    __hip_atomic_store(&g_ps[b], lg2, __ATOMIC_RELEASE, __HIP_MEMORY_SCOPE_AGENT);
    int old = __hip_atomic_fetch_add(&g_ctr, 1, __ATOMIC_ACQ_REL,
                                     __HIP_MEMORY_SCOPE_AGENT);
    if (old == B - 1) {
      float s = 0.0f;
      for (int i = 0; i < B; ++i)
        s += __hip_atomic_load(&g_ps[i], __ATOMIC_ACQUIRE, __HIP_MEMORY_SCOPE_AGENT);
      out[0] = -s * (LN2 / B);
      __hip_atomic_store(&g_ctr, 0, __ATOMIC_RELAXED, __HIP_MEMORY_SCOPE_AGENT);
    }
  }
#undef LOADG
#undef STEPS
}

extern "C" void kernel_launch(void* const* d_in, const int* in_sizes, int n_in,
                              void* d_out, int out_size, void* d_ws, size_t ws_size,
                              hipStream_t stream) {
  const float* logits = (const float*)d_in[0];
  const int* labels = (const int*)d_in[1];
  const int* logit_len = (const int*)d_in[2];
  const int* label_len = (const int*)d_in[3];
  float* out = (float*)d_out;

  hipLaunchKernelGGL(gather_kernel, dim3((MM4 + 3) / 4, B), dim3(256), 0, stream,
                     logits, labels, logit_len, label_len);
  hipLaunchKernelGGL(dp_kernel, dim3(B), dim3(64), 0, stream,
                     logit_len, label_len, out);
}

// Round 18
// 30.223 us; speedup vs baseline: 1.2773x; 1.0157x over previous
//
#include <hip/hip_runtime.h>

// RNNT (Transducer) alpha-recursion loss, forward, mean reduction.
// B=4, T=512, U=100 (U+1=101 cols), V=1024, fp32.
//
// R18 = R17 (meet-in-the-middle) with the pair-combine guard FIXED:
// g_pair must be incremented ONCE PER BLOCK (lane 0) and the result
// broadcast; R17 let all 64 lanes increment -> combine ran in the wrong
// block with one active lane (absmax 211).
//
// MITM: answer = sum_u alpha[s_mid](u) * beta[s_mid](u).
//   alpha: forward diag 0 -> s_mid (R14's verified 4-step fused DP, shr).
//   beta:  b[t][u] = blank[t][u]*b[t+1][u] + emit[t][u]*b[t][u+1],
//          backward diag smax -> s_mid (mirrored 4-step fusion, shl).
// Both run CONCURRENTLY in separate blocks -> sequential chain halves
// (~76 macros/side vs 153). Pair combined by the 2nd-arriving BLOCK via a
// full-wave f64 dot product.
// Per-macro rounded-mean normalization; scales summed at combine.

constexpr int B = 4, T = 512, U = 100, Up1 = 101, V = 1024;
constexpr int DIAGS = T + U;        // 612
constexpr int MMH = 80;             // padded macro slots per side
constexpr int W = 4;                // macros per load group (mod-3 pipe)
constexpr float LOG2E = 1.44269504088896340736f;
constexpr float LN2 = 0.69314718055994530942f;

__device__ double2 g_D1[(size_t)B * MMH * 64];  // alpha {dA, dB1}
__device__ double2 g_D2[(size_t)B * MMH * 64];  // alpha {dA1,dB2}
__device__ double2 g_D3[(size_t)B * MMH * 64];  // alpha {dA2,eB }
__device__ double2 g_D4[(size_t)B * MMH * 64];  // alpha {eA, eB1}
__device__ double2 g_D5[(size_t)B * MMH * 64];  // alpha {eA1,eB2}
__device__ double2 g_E1[(size_t)B * MMH * 64];  // beta  {dA, dB }
__device__ double2 g_E2[(size_t)B * MMH * 64];  // beta  {dA1,dB1}
__device__ double2 g_E3[(size_t)B * MMH * 64];  // beta  {dA2,eB }
__device__ double2 g_E4[(size_t)B * MMH * 64];  // beta  {eA1,eB1}
__device__ double2 g_E5[(size_t)B * MMH * 64];  // beta  {eA2,eB2}
__device__ double2 g_LB1[3][B * 64];            // beta tail {x,z}
__device__ double2 g_LB2[3][B * 64];            // beta tail {y,w}
__device__ float g_mmA[B * MMH];                // alpha per-macro scale
__device__ float g_mmB[B * MMH];                // beta per-macro scale
__device__ float g_lastmB[B][3];                // beta tail scales
__device__ double2 g_half[2][B][64];            // per-side final state
__device__ float g_hms[2][B];                   // per-side scale sum
__device__ int g_pair[B];                       // pair arrival counter
__device__ float g_ps[B];
__device__ int g_ctr = 0;

__device__ __forceinline__ int clampi(int x, int lo, int hi) {
  return x < lo ? lo : (x > hi ? hi : x);
}
__device__ __forceinline__ float fexp2(float x) {
  float r; asm("v_exp_f32 %0, %1" : "=v"(r) : "v"(x)); return r;
}
__device__ __forceinline__ float flog2(float x) {
  float r; asm("v_log_f32 %0, %1" : "=v"(r) : "v"(x)); return r;
}
// lane l <- lane l-1 (verified direction, R2+)
__device__ __forceinline__ double wave_shr1_f64(double x) {
  int hi = __double2hiint(x), lo = __double2loint(x);
  hi = __builtin_amdgcn_update_dpp(hi, hi, 0x138, 0xF, 0xF, false);
  lo = __builtin_amdgcn_update_dpp(lo, lo, 0x138, 0xF, 0xF, false);
  return __hiloint2double(hi, lo);
}
// lane l <- lane l+1 (mirror; lane 63 keeps own, killed by 0-coeffs)
__device__ __forceinline__ double wave_shl1_f64(double x) {
  int hi = __double2hiint(x), lo = __double2loint(x);
  hi = __builtin_amdgcn_update_dpp(hi, hi, 0x130, 0xF, 0xF, false);
  lo = __builtin_amdgcn_update_dpp(lo, lo, 0x130, 0xF, 0xF, false);
  return __hiloint2double(hi, lo);
}

__global__ __launch_bounds__(256) void gather_kernel(const float* __restrict__ logits,
                                                     const int* __restrict__ labels,
                                                     const int* __restrict__ logit_len,
                                                     const int* __restrict__ label_len) {
  const int b = blockIdx.y;
  const int mr = blockIdx.x * 4 + (threadIdx.x >> 6);   // macro slot
  const int l = threadIdx.x & 63;
  if (mr >= MMH) return;
  const int Tb = clampi(logit_len[b], 1, T);
  const int Ub = clampi(label_len[b], 1, U);
  const int smax = Tb - 1 + Ub;
  const int s_mid = (smax >> 1) & ~3;  // alpha steps (mult of 4)
  const int MqA = s_mid >> 2;
  const int nbs = smax - s_mid;        // beta steps
  const int MqB = nbs >> 2, remB = nbs & 3;

  const float* lg = logits + (size_t)b * T * Up1 * V;
  const int u0 = 2 * l, u1 = u0 + 1;
  int labz = 0, labw = 0, labv = 0;
  if (u0 >= 1 && u0 <= U) labz = clampi(labels[b * U + (u0 - 1)], 0, V - 1);
  if (u0 < U)             labw = clampi(labels[b * U + u0], 0, V - 1);
  if (u1 < U)             labv = clampi(labels[b * U + u1], 0, V - 1);

  // ---- alpha raw row (forward semantics, R14-verified) ----
#define RAWROWA(r, vx, vy, vz, vw, bx, by, bz, bw)                             \
  {                                                                            \
    vx = vy = vz = vw = 0.f; bx = by = bz = bw = false;                        \
    int tx = (r) - u0;                                                         \
    if (u0 <= Ub && tx >= 0 && tx <= Tb - 1) { vx = LOG2E * lg[((size_t)tx * Up1 + u0) * V]; bx = true; } \
    int ty = (r) - u1;                                                         \
    if (u1 <= Ub && ty >= 0 && ty <= Tb - 1) { vy = LOG2E * lg[((size_t)ty * Up1 + u1) * V]; by = true; } \
    int tz = (r) - u0 + 1;                                                     \
    if (u0 >= 1 && u0 <= Ub && tz >= 0 && tz <= Tb - 1) { vz = LOG2E * lg[((size_t)tz * Up1 + (u0 - 1)) * V + labz]; bz = true; } \
    int tw = (r) - u0;                                                         \
    if (u0 <= Ub - 1 && tw >= 0 && tw <= Tb - 1) { vw = LOG2E * lg[((size_t)tw * Up1 + u0) * V + labw]; bw = true; } \
  }
  // ---- beta raw row: x=blank(t,u0) z=emit(t,u0) y=blank(t1,u1) w=emit(t1,u1)
#define RAWROWB(r, vx, vy, vz, vw, bx, by, bz, bw)                             \
  {                                                                            \
    vx = vy = vz = vw = 0.f; bx = by = bz = bw = false;                        \
    int tx = (r) - u0;                                                         \
    if (u0 <= Ub && tx >= 0 && tx <= Tb - 1) {                                 \
      vx = LOG2E * lg[((size_t)tx * Up1 + u0) * V]; bx = true;                 \
      if (u0 <= Ub - 1) { vz = LOG2E * lg[((size_t)tx * Up1 + u0) * V + labw]; bz = true; } \
    }                                                                          \
    int ty = (r) - u1;                                                         \
    if (u1 <= Ub && ty >= 0 && ty <= Tb - 1) {                                 \
      vy = LOG2E * lg[((size_t)ty * Up1 + u1) * V]; by = true;                 \
      if (u1 <= Ub - 1) { vw = LOG2E * lg[((size_t)ty * Up1 + u1) * V + labv]; bw = true; } \
    }                                                                          \
  }
#define NORM8(vx, vy, vz, vw, bx, by, bz, bw, m)                               \
  {                                                                            \
    float s_ = 0.f, c_ = 0.f;                                                  \
    _Pragma("unroll")                                                          \
    for (int k = 0; k < 4; ++k) {                                              \
      s_ += (bx[k] ? vx[k] : 0.f) + (by[k] ? vy[k] : 0.f) +                    \
            (bz[k] ? vz[k] : 0.f) + (bw[k] ? vw[k] : 0.f);                     \
      c_ += (float)((int)bx[k] + (int)by[k] + (int)bz[k] + (int)bw[k]);        \
    }                                                                          \
    for (int off = 32; off; off >>= 1) {                                       \
      s_ += __shfl_xor(s_, off, 64); c_ += __shfl_xor(c_, off, 64);            \
    }                                                                          \
    m = (c_ > 0.f) ? rintf(s_ / c_) : 0.f;                                     \
  }

  // =================== ALPHA side (slot mr) ===================
  {
    const size_t idx = ((size_t)b * MMH + mr) * 64 + l;
    if (mr < MqA) {
      float vx[4], vy[4], vz[4], vw[4];
      bool bx[4], by[4], bz[4], bw[4];
#pragma unroll
      for (int k = 0; k < 4; ++k)
        RAWROWA(4 * mr + k, vx[k], vy[k], vz[k], vw[k], bx[k], by[k], bz[k], bw[k]);
      float m; NORM8(vx, vy, vz, vw, bx, by, bz, bw, m);
      float fX[4], fY[4], fZ[4], fW[4];
#pragma unroll
      for (int k = 0; k < 4; ++k) {
        fX[k] = bx[k] ? fexp2(vx[k] - m) : 0.f;
        fY[k] = by[k] ? fexp2(vy[k] - m) : 0.f;
        fZ[k] = bz[k] ? fexp2(vz[k] - m) : 0.f;
        fW[k] = bw[k] ? fexp2(vw[k] - m) : 0.f;
      }
#define COMP2A(P, Q, R_, S, Tc, Uc, i, jj)                                     \
      {                                                                        \
        float y1n = __shfl_up(fY[i], 1, 64);                                   \
        float w1n = __shfl_up(fW[i], 1, 64);                                   \
        double X1 = fX[i], Y1 = fY[i], Z1 = fZ[i], W1 = fW[i];                 \
        double X2 = fX[jj], Y2 = fY[jj], Z2 = fZ[jj], W2 = fW[jj];             \
        P = X2 * X1; Q = X2 * Z1 + Z2 * (double)y1n; R_ = Z2 * (double)w1n;    \
        S = Y2 * Y1; Tc = W2 * X1 + Y2 * W1; Uc = W2 * Z1;                     \
      }
      double Mp, Mq_, Mr, Ms, Mt, Mu, Np, Nq, Nr, Ns, Nt, Nu;
      COMP2A(Mp, Mq_, Mr, Ms, Mt, Mu, 0, 1);
      COMP2A(Np, Nq, Nr, Ns, Nt, Nu, 2, 3);
#undef COMP2A
      double Mp1 = __shfl_up(Mp, 1, 64), Mq1 = __shfl_up(Mq_, 1, 64);
      double Mr1 = __shfl_up(Mr, 1, 64), Ms1 = __shfl_up(Ms, 1, 64);
      double Mt1 = __shfl_up(Mt, 1, 64), Mu1 = __shfl_up(Mu, 1, 64);
      g_D1[idx] = make_double2(Np * Mp, Np * Mq_ + Nq * Ms1);
      g_D2[idx] = make_double2(Np * Mr + Nq * Mt1 + Nr * Mp1, Nq * Mu1 + Nr * Mq1);
      g_D3[idx] = make_double2(Nr * Mr1, Ns * Ms);
      g_D4[idx] = make_double2(Ns * Mt + Nt * Mp, Ns * Mu + Nt * Mq_ + Nu * Ms1);
      g_D5[idx] = make_double2(Nt * Mr + Nu * Mt1, Nu * Mu1);
      if (l == 0) g_mmA[b * MMH + mr] = 4.f * m;
    } else {
      g_D1[idx] = make_double2(1.0, 0.0);
      g_D2[idx] = make_double2(0.0, 0.0);
      g_D3[idx] = make_double2(0.0, 1.0);
      g_D4[idx] = make_double2(0.0, 0.0);
      g_D5[idx] = make_double2(0.0, 0.0);
      if (l == 0) g_mmA[b * MMH + mr] = 0.f;
    }
  }

  // =================== BETA side (slot mr) ===================
  {
    const size_t idx = ((size_t)b * MMH + mr) * 64 + l;
    if (mr < MqB) {
      // rows consumed (in order): smax-4mr-1-k, k=0..3
      float vx[4], vy[4], vz[4], vw[4];
      bool bx[4], by[4], bz[4], bw[4];
#pragma unroll
      for (int k = 0; k < 4; ++k)
        RAWROWB(smax - 4 * mr - 1 - k, vx[k], vy[k], vz[k], vw[k], bx[k], by[k], bz[k], bw[k]);
      float m; NORM8(vx, vy, vz, vw, bx, by, bz, bw, m);
      float fX[4], fY[4], fZ[4], fW[4];
#pragma unroll
      for (int k = 0; k < 4; ++k) {
        fX[k] = bx[k] ? fexp2(vx[k] - m) : 0.f;
        fY[k] = by[k] ? fexp2(vy[k] - m) : 0.f;
        fZ[k] = bz[k] ? fexp2(vz[k] - m) : 0.f;
        fW[k] = bw[k] ? fexp2(vw[k] - m) : 0.f;
      }
      // beta 2-step: first=f (applied first), second=ss
#define COMP2B(P, Q, R_, S, Tc, Uc, f, ss)                                     \
      {                                                                        \
        float xfd = __shfl_down(fX[f], 1, 64);                                 \
        float zfd = __shfl_down(fZ[f], 1, 64);                                 \
        double Xf = fX[f], Yf = fY[f], Zf = fZ[f], Wf = fW[f];                 \
        double Xs = fX[ss], Ys = fY[ss], Zs = fZ[ss], Ws = fW[ss];             \
        P = Xs * Xf; Q = Xs * Zf + Zs * Yf; R_ = Zs * Wf;                      \
        S = Ys * Yf; Tc = Ys * Wf + Ws * (double)xfd; Uc = Ws * (double)zfd;   \
      }
      double Mp, Mq_, Mr, Ms, Mt, Mu, Np, Nq, Nr, Ns, Nt, Nu;
      COMP2B(Mp, Mq_, Mr, Ms, Mt, Mu, 0, 1);
      COMP2B(Np, Nq, Nr, Ns, Nt, Nu, 2, 3);
#undef COMP2B
      double Mp1 = __shfl_down(Mp, 1, 64), Mq1 = __shfl_down(Mq_, 1, 64);
      double Mr1 = __shfl_down(Mr, 1, 64), Ms1 = __shfl_down(Ms, 1, 64);
      double Mt1 = __shfl_down(Mt, 1, 64), Mu1 = __shfl_down(Mu, 1, 64);
      g_E1[idx] = make_double2(Np * Mp, Np * Mq_ + Nq * Ms);
      g_E2[idx] = make_double2(Np * Mr + Nq * Mt + Nr * Mp1, Nq * Mu + Nr * Mq1);
      g_E3[idx] = make_double2(Nr * Mr1, Ns * Ms);
      g_E4[idx] = make_double2(Ns * Mt + Nt * Mp1, Ns * Mu + Nt * Mq1 + Nu * Ms1);
      g_E5[idx] = make_double2(Nt * Mr1 + Nu * Mt1, Nu * Mu1);
      if (l == 0) g_mmB[b * MMH + mr] = 4.f * m;
    } else {
      g_E1[idx] = make_double2(1.0, 0.0);
      g_E2[idx] = make_double2(0.0, 0.0);
      g_E3[idx] = make_double2(0.0, 1.0);
      g_E4[idx] = make_double2(0.0, 0.0);
      g_E5[idx] = make_double2(0.0, 0.0);
      if (l == 0) g_mmB[b * MMH + mr] = 0.f;

      if (mr == MqB) {                  // beta tail rows smax-4MqB-1-j
        for (int j = 0; j < remB; ++j) {
          int r = smax - 4 * MqB - 1 - j;
          float vx, vy, vz, vw; bool bx, by, bz, bw;
          RAWROWB(r, vx, vy, vz, vw, bx, by, bz, bw);
          float s_ = (bx ? vx : 0.f) + (by ? vy : 0.f) + (bz ? vz : 0.f) + (bw ? vw : 0.f);
          float c_ = (float)((int)bx + (int)by + (int)bz + (int)bw);
          for (int off = 32; off; off >>= 1) { s_ += __shfl_xor(s_, off, 64); c_ += __shfl_xor(c_, off, 64); }
          float m = (c_ > 0.f) ? rintf(s_ / c_) : 0.f;
          g_LB1[j][b * 64 + l] = make_double2(bx ? (double)fexp2(vx - m) : 0.0,
                                              bz ? (double)fexp2(vz - m) : 0.0);
          g_LB2[j][b * 64 + l] = make_double2(by ? (double)fexp2(vy - m) : 0.0,
                                              bw ? (double)fexp2(vw - m) : 0.0);
          if (l == 0) g_lastmB[b][j] = m;
        }
      }
    }
  }
#undef RAWROWA
#undef RAWROWB
#undef NORM8
}

__global__ __launch_bounds__(64, 1)
void dp_kernel(const int* __restrict__ logit_len,
               const int* __restrict__ label_len,
               float* __restrict__ out) {
  const int blk = blockIdx.x;          // 0..7
  const int b = blk & 3, side = blk >> 2;
  const int lane = threadIdx.x;
  const int Tb = clampi(logit_len[b], 1, T);
  const int Ub = clampi(label_len[b], 1, U);
  const int smax = Tb - 1 + Ub;
  const int s_mid = (smax >> 1) & ~3;
  const int MqA = s_mid >> 2;
  const int nbs = smax - s_mid;
  const int MqB = nbs >> 2, remB = nbs & 3;

  double A, Bc;
  float msum = 0.f;

  double2 a1[W], a2[W], a3[W], a4[W], a5[W];
  double2 b1[W], b2[W], b3[W], b4[W], b5[W];
  double2 c1[W], c2[W], c3[W], c4[W], c5[W];

#define LOADG(P1, P2, P3, P4, P5, u1_, u2_, u3_, u4_, u5_, grp)                \
  {                                                                            \
    const size_t o_ = (size_t)(grp) * (W * 64);                                \
    _Pragma("unroll")                                                          \
    for (int j_ = 0; j_ < W; ++j_) {                                           \
      u1_[j_] = P1[o_ + j_ * 64]; u2_[j_] = P2[o_ + j_ * 64];                  \
      u3_[j_] = P3[o_ + j_ * 64]; u4_[j_] = P4[o_ + j_ * 64];                  \
      u5_[j_] = P5[o_ + j_ * 64];                                              \
    }                                                                          \
  }
#define PIPE(P1, P2, P3, P4, P5, STEPS_, NWC_)                                 \
  if (NWC_ > 0) {                                                              \
    LOADG(P1, P2, P3, P4, P5, a1, a2, a3, a4, a5, 0);                          \
    if (NWC_ > 1) LOADG(P1, P2, P3, P4, P5, b1, b2, b3, b4, b5, 1);            \
    for (int k = 0; k < NWC_; k += 3) {                                        \
      if (k + 2 < NWC_) LOADG(P1, P2, P3, P4, P5, c1, c2, c3, c4, c5, k + 2);  \
      STEPS_(a1, a2, a3, a4, a5);                                              \
      if (k + 1 < NWC_) {                                                      \
        if (k + 3 < NWC_) LOADG(P1, P2, P3, P4, P5, a1, a2, a3, a4, a5, k + 3);\
        STEPS_(b1, b2, b3, b4, b5);                                            \
        if (k + 2 < NWC_) {                                                    \
          if (k + 4 < NWC_) LOADG(P1, P2, P3, P4, P5, b1, b2, b3, b4, b5, k + 4);\
          STEPS_(c1, c2, c3, c4, c5);                                          \
        }                                                                      \
      }                                                                        \
    }                                                                          \
  }
#define STEPSA(u1_, u2_, u3_, u4_, u5_)                                        \
  {                                                                            \
    _Pragma("unroll")                                                          \
    for (int j_ = 0; j_ < W; ++j_) {                                           \
      double A1s = wave_shr1_f64(A);                                           \
      double B1s = wave_shr1_f64(Bc);                                          \
      double A2s = wave_shr1_f64(A1s);                                         \
      double B2s = wave_shr1_f64(B1s);                                         \
      double na = fma(A, u1_[j_].x, fma(B1s, u1_[j_].y,                        \
                   fma(A1s, u2_[j_].x, fma(B2s, u2_[j_].y, A2s * u3_[j_].x))));\
      double nb = fma(Bc, u3_[j_].y, fma(A, u4_[j_].x,                         \
                   fma(B1s, u4_[j_].y, fma(A1s, u5_[j_].x, B2s * u5_[j_].y))));\
      A = na; Bc = nb;                                                         \
    }                                                                          \
  }
#define STEPSB(u1_, u2_, u3_, u4_, u5_)                                        \
  {                                                                            \
    _Pragma("unroll")                                                          \
    for (int j_ = 0; j_ < W; ++j_) {                                           \
      double A1s = wave_shl1_f64(A);                                           \
      double B1s = wave_shl1_f64(Bc);                                          \
      double A2s = wave_shl1_f64(A1s);                                         \
      double B2s = wave_shl1_f64(B1s);                                         \
      double na = fma(A, u1_[j_].x, fma(Bc, u1_[j_].y,                         \
                   fma(A1s, u2_[j_].x, fma(B1s, u2_[j_].y, A2s * u3_[j_].x))));\
      double nb = fma(Bc, u3_[j_].y, fma(A1s, u4_[j_].x,                       \
                   fma(B1s, u4_[j_].y, fma(A2s, u5_[j_].x, B2s * u5_[j_].y))));\
      A = na; Bc = nb;                                                         \
    }                                                                          \
  }

  if (side == 0) {
    // ---------------- alpha: diag 0 -> s_mid ----------------
    A = (lane == 0) ? 1.0 : 0.0;
    Bc = 0.0;
    const double2* D1 = g_D1 + (size_t)b * MMH * 64 + lane;
    const double2* D2 = g_D2 + (size_t)b * MMH * 64 + lane;
    const double2* D3 = g_D3 + (size_t)b * MMH * 64 + lane;
    const double2* D4 = g_D4 + (size_t)b * MMH * 64 + lane;
    const double2* D5 = g_D5 + (size_t)b * MMH * 64 + lane;
    const int NWC = (MqA + W - 1) / W;
    PIPE(D1, D2, D3, D4, D5, STEPSA, NWC);
    for (int mI = lane; mI < MqA; mI += 64) msum += g_mmA[b * MMH + mI];
    for (int off = 32; off; off >>= 1) msum += __shfl_xor(msum, off, 64);
  } else {
    // ---------------- beta: diag smax -> s_mid ----------------
    const int aL = Ub >> 1;
    A = (!(Ub & 1) && lane == aL) ? 1.0 : 0.0;
    Bc = ((Ub & 1) && lane == aL) ? 1.0 : 0.0;
    const double2* E1 = g_E1 + (size_t)b * MMH * 64 + lane;
    const double2* E2 = g_E2 + (size_t)b * MMH * 64 + lane;
    const double2* E3 = g_E3 + (size_t)b * MMH * 64 + lane;
    const double2* E4 = g_E4 + (size_t)b * MMH * 64 + lane;
    const double2* E5 = g_E5 + (size_t)b * MMH * 64 + lane;
    const int NWC = (MqB + W - 1) / W;
    PIPE(E1, E2, E3, E4, E5, STEPSB, NWC);
    for (int j = 0; j < remB; ++j) {    // tail raw beta steps
      double2 L1 = g_LB1[j][b * 64 + lane];   // {x, z}
      double2 L2 = g_LB2[j][b * 64 + lane];   // {y, w}
      double shlA = wave_shl1_f64(A);
      double na = fma(A, L1.x, Bc * L1.y);
      double nb = fma(Bc, L2.x, shlA * L2.y);
      A = na; Bc = nb;
    }
    for (int mI = lane; mI < MqB; mI += 64) msum += g_mmB[b * MMH + mI];
    for (int off = 32; off; off >>= 1) msum += __shfl_xor(msum, off, 64);
    for (int j = 0; j < remB; ++j) msum += g_lastmB[b][j];
  }

  // ---------------- pair combine (FIXED: one add per BLOCK) ----------------
  g_half[side][b][lane] = make_double2(A, Bc);
  if (lane == 0) g_hms[side][b] = msum;
  int old = 0;
  if (lane == 0)
    old = __hip_atomic_fetch_add(&g_pair[b], 1, __ATOMIC_ACQ_REL,
                                 __HIP_MEMORY_SCOPE_AGENT);
  old = __shfl(old, 0, 64);            // broadcast to the whole wave
  if (old == 1) {                      // second-arriving BLOCK combines
    const int p = 1 - side;
    double2 ps = g_half[p][b][lane];
    float pm = g_hms[p][b];
    double dot = A * ps.x + Bc * ps.y;
    for (int off = 32; off; off >>= 1) dot += __shfl_xor(dot, off, 64);
    int ev = ((__double2hiint(dot) >> 20) & 0x7ff) - 1023;
    double mant = ldexp(dot, -ev);
    float lg2 = (float)ev + flog2((float)mant) + msum + pm;
    if (lane == 0) {
      __hip_atomic_store(&g_pair[b], 0, __ATOMIC_RELAXED, __HIP_MEMORY_SCOPE_AGENT);
      __hip_atomic_store(&g_ps[b], lg2, __ATOMIC_RELEASE, __HIP_MEMORY_SCOPE_AGENT);
      int o2 = __hip_atomic_fetch_add(&g_ctr, 1, __ATOMIC_ACQ_REL,
                                      __HIP_MEMORY_SCOPE_AGENT);
      if (o2 == B - 1) {
        float s = 0.0f;
        for (int i = 0; i < B; ++i)
          s += __hip_atomic_load(&g_ps[i], __ATOMIC_ACQUIRE, __HIP_MEMORY_SCOPE_AGENT);
        out[0] = -s * (LN2 / B);
        __hip_atomic_store(&g_ctr, 0, __ATOMIC_RELAXED, __HIP_MEMORY_SCOPE_AGENT);
      }
    }
  }
#undef LOADG
#undef PIPE
#undef STEPSA
#undef STEPSB
}

extern "C" void kernel_launch(void* const* d_in, const int* in_sizes, int n_in,
                              void* d_out, int out_size, void* d_ws, size_t ws_size,
                              hipStream_t stream) {
  const float* logits = (const float*)d_in[0];
  const int* labels = (const int*)d_in[1];
  const int* logit_len = (const int*)d_in[2];
  const int* label_len = (const int*)d_in[3];
  float* out = (float*)d_out;

  hipLaunchKernelGGL(gather_kernel, dim3(MMH / 4, B), dim3(256), 0, stream,
                     logits, labels, logit_len, label_len);
  hipLaunchKernelGGL(dp_kernel, dim3(2 * B), dim3(64), 0, stream,
                     logit_len, label_len, out);
}

// Round 19
// 25.392 us; speedup vs baseline: 1.5204x; 1.1903x over previous
//
#include <hip/hip_runtime.h>

// RNNT (Transducer) alpha-recursion loss, forward, mean reduction.
// B=4, T=512, U=100 (U+1=101 cols), V=1024, fp32.
//
// R19 = R18 (meet-in-the-middle, fixed pair-combine) with the GATHER SPLIT
// BY SIDE: blockIdx.z in {0,1} selects alpha- or beta-staging, so each
// block does HALF of R18's serial work (R18 doubled the gather by staging
// both sides per block, masking MITM's DP halving: 6->12us gather while
// DP 14->7.5us kept the total flat at ~30).
//
// MITM: answer = sum_u alpha[s_mid](u) * beta[s_mid](u).
//   alpha: forward diag 0 -> s_mid (R14's verified 4-step fused DP, shr).
//   beta:  b[t][u] = blank[t][u]*b[t+1][u] + emit[t][u]*b[t][u+1],
//          backward diag smax -> s_mid (mirrored 4-step fusion, shl).
// Both DP sides run CONCURRENTLY (8 blocks); pair combined by the
// 2nd-arriving block via a full-wave f64 dot product.
// Per-macro rounded-mean normalization; scales summed at combine.

constexpr int B = 4, T = 512, U = 100, Up1 = 101, V = 1024;
constexpr int DIAGS = T + U;        // 612
constexpr int MMH = 80;             // padded macro slots per side
constexpr int W = 4;                // macros per load group (mod-3 pipe)
constexpr float LOG2E = 1.44269504088896340736f;
constexpr float LN2 = 0.69314718055994530942f;

__device__ double2 g_D1[(size_t)B * MMH * 64];  // alpha {dA, dB1}
__device__ double2 g_D2[(size_t)B * MMH * 64];  // alpha {dA1,dB2}
__device__ double2 g_D3[(size_t)B * MMH * 64];  // alpha {dA2,eB }
__device__ double2 g_D4[(size_t)B * MMH * 64];  // alpha {eA, eB1}
__device__ double2 g_D5[(size_t)B * MMH * 64];  // alpha {eA1,eB2}
__device__ double2 g_E1[(size_t)B * MMH * 64];  // beta  {dA, dB }
__device__ double2 g_E2[(size_t)B * MMH * 64];  // beta  {dA1,dB1}
__device__ double2 g_E3[(size_t)B * MMH * 64];  // beta  {dA2,eB }
__device__ double2 g_E4[(size_t)B * MMH * 64];  // beta  {eA1,eB1}
__device__ double2 g_E5[(size_t)B * MMH * 64];  // beta  {eA2,eB2}
__device__ double2 g_LB1[3][B * 64];            // beta tail {x,z}
__device__ double2 g_LB2[3][B * 64];            // beta tail {y,w}
__device__ float g_mmA[B * MMH];                // alpha per-macro scale
__device__ float g_mmB[B * MMH];                // beta per-macro scale
__device__ float g_lastmB[B][3];                // beta tail scales
__device__ double2 g_half[2][B][64];            // per-side final state
__device__ float g_hms[2][B];                   // per-side scale sum
__device__ int g_pair[B];                       // pair arrival counter
__device__ float g_ps[B];
__device__ int g_ctr = 0;

__device__ __forceinline__ int clampi(int x, int lo, int hi) {
  return x < lo ? lo : (x > hi ? hi : x);
}
__device__ __forceinline__ float fexp2(float x) {
  float r; asm("v_exp_f32 %0, %1" : "=v"(r) : "v"(x)); return r;
}
__device__ __forceinline__ float flog2(float x) {
  float r; asm("v_log_f32 %0, %1" : "=v"(r) : "v"(x)); return r;
}
// lane l <- lane l-1 (verified direction, R2+)
__device__ __forceinline__ double wave_shr1_f64(double x) {
  int hi = __double2hiint(x), lo = __double2loint(x);
  hi = __builtin_amdgcn_update_dpp(hi, hi, 0x138, 0xF, 0xF, false);
  lo = __builtin_amdgcn_update_dpp(lo, lo, 0x138, 0xF, 0xF, false);
  return __hiloint2double(hi, lo);
}
// lane l <- lane l+1 (mirror; lane 63 keeps own, killed by 0-coeffs)
__device__ __forceinline__ double wave_shl1_f64(double x) {
  int hi = __double2hiint(x), lo = __double2loint(x);
  hi = __builtin_amdgcn_update_dpp(hi, hi, 0x130, 0xF, 0xF, false);
  lo = __builtin_amdgcn_update_dpp(lo, lo, 0x130, 0xF, 0xF, false);
  return __hiloint2double(hi, lo);
}

__global__ __launch_bounds__(256) void gather_kernel(const float* __restrict__ logits,
                                                     const int* __restrict__ labels,
                                                     const int* __restrict__ logit_len,
                                                     const int* __restrict__ label_len) {
  const int b = blockIdx.y;
  const int side = blockIdx.z;          // 0 = alpha staging, 1 = beta staging
  const int mr = blockIdx.x * 4 + (threadIdx.x >> 6);   // macro slot
  const int l = threadIdx.x & 63;
  if (mr >= MMH) return;
  const int Tb = clampi(logit_len[b], 1, T);
  const int Ub = clampi(label_len[b], 1, U);
  const int smax = Tb - 1 + Ub;
  const int s_mid = (smax >> 1) & ~3;  // alpha steps (mult of 4)
  const int MqA = s_mid >> 2;
  const int nbs = smax - s_mid;        // beta steps
  const int MqB = nbs >> 2, remB = nbs & 3;

  const float* lg = logits + (size_t)b * T * Up1 * V;
  const int u0 = 2 * l, u1 = u0 + 1;
  int labz = 0, labw = 0, labv = 0;
  if (u0 >= 1 && u0 <= U) labz = clampi(labels[b * U + (u0 - 1)], 0, V - 1);
  if (u0 < U)             labw = clampi(labels[b * U + u0], 0, V - 1);
  if (u1 < U)             labv = clampi(labels[b * U + u1], 0, V - 1);

  // ---- alpha raw row (forward semantics, R14-verified) ----
#define RAWROWA(r, vx, vy, vz, vw, bx, by, bz, bw)                             \
  {                                                                            \
    vx = vy = vz = vw = 0.f; bx = by = bz = bw = false;                        \
    int tx = (r) - u0;                                                         \
    if (u0 <= Ub && tx >= 0 && tx <= Tb - 1) { vx = LOG2E * lg[((size_t)tx * Up1 + u0) * V]; bx = true; } \
    int ty = (r) - u1;                                                         \
    if (u1 <= Ub && ty >= 0 && ty <= Tb - 1) { vy = LOG2E * lg[((size_t)ty * Up1 + u1) * V]; by = true; } \
    int tz = (r) - u0 + 1;                                                     \
    if (u0 >= 1 && u0 <= Ub && tz >= 0 && tz <= Tb - 1) { vz = LOG2E * lg[((size_t)tz * Up1 + (u0 - 1)) * V + labz]; bz = true; } \
    int tw = (r) - u0;                                                         \
    if (u0 <= Ub - 1 && tw >= 0 && tw <= Tb - 1) { vw = LOG2E * lg[((size_t)tw * Up1 + u0) * V + labw]; bw = true; } \
  }
  // ---- beta raw row: x=blank(t,u0) z=emit(t,u0) y=blank(t1,u1) w=emit(t1,u1)
#define RAWROWB(r, vx, vy, vz, vw, bx, by, bz, bw)                             \
  {                                                                            \
    vx = vy = vz = vw = 0.f; bx = by = bz = bw = false;                        \
    int tx = (r) - u0;                                                         \
    if (u0 <= Ub && tx >= 0 && tx <= Tb - 1) {                                 \
      vx = LOG2E * lg[((size_t)tx * Up1 + u0) * V]; bx = true;                 \
      if (u0 <= Ub - 1) { vz = LOG2E * lg[((size_t)tx * Up1 + u0) * V + labw]; bz = true; } \
    }                                                                          \
    int ty = (r) - u1;                                                         \
    if (u1 <= Ub && ty >= 0 && ty <= Tb - 1) {                                 \
      vy = LOG2E * lg[((size_t)ty * Up1 + u1) * V]; by = true;                 \
      if (u1 <= Ub - 1) { vw = LOG2E * lg[((size_t)ty * Up1 + u1) * V + labv]; bw = true; } \
    }                                                                          \
  }
#define NORM8(vx, vy, vz, vw, bx, by, bz, bw, m)                               \
  {                                                                            \
    float s_ = 0.f, c_ = 0.f;                                                  \
    _Pragma("unroll")                                                          \
    for (int k = 0; k < 4; ++k) {                                              \
      s_ += (bx[k] ? vx[k] : 0.f) + (by[k] ? vy[k] : 0.f) +                    \
            (bz[k] ? vz[k] : 0.f) + (bw[k] ? vw[k] : 0.f);                     \
      c_ += (float)((int)bx[k] + (int)by[k] + (int)bz[k] + (int)bw[k]);        \
    }                                                                          \
    for (int off = 32; off; off >>= 1) {                                       \
      s_ += __shfl_xor(s_, off, 64); c_ += __shfl_xor(c_, off, 64);            \
    }                                                                          \
    m = (c_ > 0.f) ? rintf(s_ / c_) : 0.f;                                     \
  }

  if (side == 0) {
    // =================== ALPHA staging (slot mr) ===================
    const size_t idx = ((size_t)b * MMH + mr) * 64 + l;
    if (mr < MqA) {
      float vx[4], vy[4], vz[4], vw[4];
      bool bx[4], by[4], bz[4], bw[4];
#pragma unroll
      for (int k = 0; k < 4; ++k)
        RAWROWA(4 * mr + k, vx[k], vy[k], vz[k], vw[k], bx[k], by[k], bz[k], bw[k]);
      float m; NORM8(vx, vy, vz, vw, bx, by, bz, bw, m);
      float fX[4], fY[4], fZ[4], fW[4];
#pragma unroll
      for (int k = 0; k < 4; ++k) {
        fX[k] = bx[k] ? fexp2(vx[k] - m) : 0.f;
        fY[k] = by[k] ? fexp2(vy[k] - m) : 0.f;
        fZ[k] = bz[k] ? fexp2(vz[k] - m) : 0.f;
        fW[k] = bw[k] ? fexp2(vw[k] - m) : 0.f;
      }
#define COMP2A(P, Q, R_, S, Tc, Uc, i, jj)                                     \
      {                                                                        \
        float y1n = __shfl_up(fY[i], 1, 64);                                   \
        float w1n = __shfl_up(fW[i], 1, 64);                                   \
        double X1 = fX[i], Y1 = fY[i], Z1 = fZ[i], W1 = fW[i];                 \
        double X2 = fX[jj], Y2 = fY[jj], Z2 = fZ[jj], W2 = fW[jj];             \
        P = X2 * X1; Q = X2 * Z1 + Z2 * (double)y1n; R_ = Z2 * (double)w1n;    \
        S = Y2 * Y1; Tc = W2 * X1 + Y2 * W1; Uc = W2 * Z1;                     \
      }
      double Mp, Mq_, Mr, Ms, Mt, Mu, Np, Nq, Nr, Ns, Nt, Nu;
      COMP2A(Mp, Mq_, Mr, Ms, Mt, Mu, 0, 1);
      COMP2A(Np, Nq, Nr, Ns, Nt, Nu, 2, 3);
#undef COMP2A
      double Mp1 = __shfl_up(Mp, 1, 64), Mq1 = __shfl_up(Mq_, 1, 64);
      double Mr1 = __shfl_up(Mr, 1, 64), Ms1 = __shfl_up(Ms, 1, 64);
      double Mt1 = __shfl_up(Mt, 1, 64), Mu1 = __shfl_up(Mu, 1, 64);
      g_D1[idx] = make_double2(Np * Mp, Np * Mq_ + Nq * Ms1);
      g_D2[idx] = make_double2(Np * Mr + Nq * Mt1 + Nr * Mp1, Nq * Mu1 + Nr * Mq1);
      g_D3[idx] = make_double2(Nr * Mr1, Ns * Ms);
      g_D4[idx] = make_double2(Ns * Mt + Nt * Mp, Ns * Mu + Nt * Mq_ + Nu * Ms1);
      g_D5[idx] = make_double2(Nt * Mr + Nu * Mt1, Nu * Mu1);
      if (l == 0) g_mmA[b * MMH + mr] = 4.f * m;
    } else {
      g_D1[idx] = make_double2(1.0, 0.0);
      g_D2[idx] = make_double2(0.0, 0.0);
      g_D3[idx] = make_double2(0.0, 1.0);
      g_D4[idx] = make_double2(0.0, 0.0);
      g_D5[idx] = make_double2(0.0, 0.0);
      if (l == 0) g_mmA[b * MMH + mr] = 0.f;
    }
  } else {
    // =================== BETA staging (slot mr) ===================
    const size_t idx = ((size_t)b * MMH + mr) * 64 + l;
    if (mr < MqB) {
      // rows consumed (in order): smax-4mr-1-k, k=0..3
      float vx[4], vy[4], vz[4], vw[4];
      bool bx[4], by[4], bz[4], bw[4];
#pragma unroll
      for (int k = 0; k < 4; ++k)
        RAWROWB(smax - 4 * mr - 1 - k, vx[k], vy[k], vz[k], vw[k], bx[k], by[k], bz[k], bw[k]);
      float m; NORM8(vx, vy, vz, vw, bx, by, bz, bw, m);
      float fX[4], fY[4], fZ[4], fW[4];
#pragma unroll
      for (int k = 0; k < 4; ++k) {
        fX[k] = bx[k] ? fexp2(vx[k] - m) : 0.f;
        fY[k] = by[k] ? fexp2(vy[k] - m) : 0.f;
        fZ[k] = bz[k] ? fexp2(vz[k] - m) : 0.f;
        fW[k] = bw[k] ? fexp2(vw[k] - m) : 0.f;
      }
      // beta 2-step: first=f (applied first), second=ss
#define COMP2B(P, Q, R_, S, Tc, Uc, f, ss)                                     \
      {                                                                        \
        float xfd = __shfl_down(fX[f], 1, 64);                                 \
        float zfd = __shfl_down(fZ[f], 1, 64);                                 \
        double Xf = fX[f], Yf = fY[f], Zf = fZ[f], Wf = fW[f];                 \
        double Xs = fX[ss], Ys = fY[ss], Zs = fZ[ss], Ws = fW[ss];             \
        P = Xs * Xf; Q = Xs * Zf + Zs * Yf; R_ = Zs * Wf;                      \
        S = Ys * Yf; Tc = Ys * Wf + Ws * (double)xfd; Uc = Ws * (double)zfd;   \
      }
      double Mp, Mq_, Mr, Ms, Mt, Mu, Np, Nq, Nr, Ns, Nt, Nu;
      COMP2B(Mp, Mq_, Mr, Ms, Mt, Mu, 0, 1);
      COMP2B(Np, Nq, Nr, Ns, Nt, Nu, 2, 3);
#undef COMP2B
      double Mp1 = __shfl_down(Mp, 1, 64), Mq1 = __shfl_down(Mq_, 1, 64);
      double Mr1 = __shfl_down(Mr, 1, 64), Ms1 = __shfl_down(Ms, 1, 64);
      double Mt1 = __shfl_down(Mt, 1, 64), Mu1 = __shfl_down(Mu, 1, 64);
      g_E1[idx] = make_double2(Np * Mp, Np * Mq_ + Nq * Ms);
      g_E2[idx] = make_double2(Np * Mr + Nq * Mt + Nr * Mp1, Nq * Mu + Nr * Mq1);
      g_E3[idx] = make_double2(Nr * Mr1, Ns * Ms);
      g_E4[idx] = make_double2(Ns * Mt + Nt * Mp1, Ns * Mu + Nt * Mq1 + Nu * Ms1);
      g_E5[idx] = make_double2(Nt * Mr1 + Nu * Mt1, Nu * Mu1);
      if (l == 0) g_mmB[b * MMH + mr] = 4.f * m;
    } else {
      g_E1[idx] = make_double2(1.0, 0.0);
      g_E2[idx] = make_double2(0.0, 0.0);
      g_E3[idx] = make_double2(0.0, 1.0);
      g_E4[idx] = make_double2(0.0, 0.0);
      g_E5[idx] = make_double2(0.0, 0.0);
      if (l == 0) g_mmB[b * MMH + mr] = 0.f;

      if (mr == MqB) {                  // beta tail rows smax-4MqB-1-j
        for (int j = 0; j < remB; ++j) {
          int r = smax - 4 * MqB - 1 - j;
          float vx, vy, vz, vw; bool bx, by, bz, bw;
          RAWROWB(r, vx, vy, vz, vw, bx, by, bz, bw);
          float s_ = (bx ? vx : 0.f) + (by ? vy : 0.f) + (bz ? vz : 0.f) + (bw ? vw : 0.f);
          float c_ = (float)((int)bx + (int)by + (int)bz + (int)bw);
          for (int off = 32; off; off >>= 1) { s_ += __shfl_xor(s_, off, 64); c_ += __shfl_xor(c_, off, 64); }
          float m = (c_ > 0.f) ? rintf(s_ / c_) : 0.f;
          g_LB1[j][b * 64 + l] = make_double2(bx ? (double)fexp2(vx - m) : 0.0,
                                              bz ? (double)fexp2(vz - m) : 0.0);
          g_LB2[j][b * 64 + l] = make_double2(by ? (double)fexp2(vy - m) : 0.0,
                                              bw ? (double)fexp2(vw - m) : 0.0);
          if (l == 0) g_lastmB[b][j] = m;
        }
      }
    }
  }
#undef RAWROWA
#undef RAWROWB
#undef NORM8
}

__global__ __launch_bounds__(64, 1)
void dp_kernel(const int* __restrict__ logit_len,
               const int* __restrict__ label_len,
               float* __restrict__ out) {
  const int blk = blockIdx.x;          // 0..7
  const int b = blk & 3, side = blk >> 2;
  const int lane = threadIdx.x;
  const int Tb = clampi(logit_len[b], 1, T);
  const int Ub = clampi(label_len[b], 1, U);
  const int smax = Tb - 1 + Ub;
  const int s_mid = (smax >> 1) & ~3;
  const int MqA = s_mid >> 2;
  const int nbs = smax - s_mid;
  const int MqB = nbs >> 2, remB = nbs & 3;

  double A, Bc;
  float msum = 0.f;

  double2 a1[W], a2[W], a3[W], a4[W], a5[W];
  double2 b1[W], b2[W], b3[W], b4[W], b5[W];
  double2 c1[W], c2[W], c3[W], c4[W], c5[W];

#define LOADG(P1, P2, P3, P4, P5, u1_, u2_, u3_, u4_, u5_, grp)                \
  {                                                                            \
    const size_t o_ = (size_t)(grp) * (W * 64);                                \
    _Pragma("unroll")                                                          \
    for (int j_ = 0; j_ < W; ++j_) {                                           \
      u1_[j_] = P1[o_ + j_ * 64]; u2_[j_] = P2[o_ + j_ * 64];                  \
      u3_[j_] = P3[o_ + j_ * 64]; u4_[j_] = P4[o_ + j_ * 64];                  \
      u5_[j_] = P5[o_ + j_ * 64];                                              \
    }                                                                          \
  }
#define PIPE(P1, P2, P3, P4, P5, STEPS_, NWC_)                                 \
  if (NWC_ > 0) {                                                              \
    LOADG(P1, P2, P3, P4, P5, a1, a2, a3, a4, a5, 0);                          \
    if (NWC_ > 1) LOADG(P1, P2, P3, P4, P5, b1, b2, b3, b4, b5, 1);            \
    for (int k = 0; k < NWC_; k += 3) {                                        \
      if (k + 2 < NWC_) LOADG(P1, P2, P3, P4, P5, c1, c2, c3, c4, c5, k + 2);  \
      STEPS_(a1, a2, a3, a4, a5);                                              \
      if (k + 1 < NWC_) {                                                      \
        if (k + 3 < NWC_) LOADG(P1, P2, P3, P4, P5, a1, a2, a3, a4, a5, k + 3);\
        STEPS_(b1, b2, b3, b4, b5);                                            \
        if (k + 2 < NWC_) {                                                    \
          if (k + 4 < NWC_) LOADG(P1, P2, P3, P4, P5, b1, b2, b3, b4, b5, k + 4);\
          STEPS_(c1, c2, c3, c4, c5);                                          \
        }                                                                      \
      }                                                                        \
    }                                                                          \
  }
#define STEPSA(u1_, u2_, u3_, u4_, u5_)                                        \
  {                                                                            \
    _Pragma("unroll")                                                          \
    for (int j_ = 0; j_ < W; ++j_) {                                           \
      double A1s = wave_shr1_f64(A);                                           \
      double B1s = wave_shr1_f64(Bc);                                          \
      double A2s = wave_shr1_f64(A1s);                                         \
      double B2s = wave_shr1_f64(B1s);                                         \
      double na = fma(A, u1_[j_].x, fma(B1s, u1_[j_].y,                        \
                   fma(A1s, u2_[j_].x, fma(B2s, u2_[j_].y, A2s * u3_[j_].x))));\
      double nb = fma(Bc, u3_[j_].y, fma(A, u4_[j_].x,                         \
                   fma(B1s, u4_[j_].y, fma(A1s, u5_[j_].x, B2s * u5_[j_].y))));\
      A = na; Bc = nb;                                                         \
    }                                                                          \
  }
#define STEPSB(u1_, u2_, u3_, u4_, u5_)                                        \
  {                                                                            \
    _Pragma("unroll")                                                          \
    for (int j_ = 0; j_ < W; ++j_) {                                           \
      double A1s = wave_shl1_f64(A);                                           \
      double B1s = wave_shl1_f64(Bc);                                          \
      double A2s = wave_shl1_f64(A1s);                                         \
      double B2s = wave_shl1_f64(B1s);                                         \
      double na = fma(A, u1_[j_].x, fma(Bc, u1_[j_].y,                         \
                   fma(A1s, u2_[j_].x, fma(B1s, u2_[j_].y, A2s * u3_[j_].x))));\
      double nb = fma(Bc, u3_[j_].y, fma(A1s, u4_[j_].x,                       \
                   fma(B1s, u4_[j_].y, fma(A2s, u5_[j_].x, B2s * u5_[j_].y))));\
      A = na; Bc = nb;                                                         \
    }                                                                          \
  }

  if (side == 0) {
    // ---------------- alpha: diag 0 -> s_mid ----------------
    A = (lane == 0) ? 1.0 : 0.0;
    Bc = 0.0;
    const double2* D1 = g_D1 + (size_t)b * MMH * 64 + lane;
    const double2* D2 = g_D2 + (size_t)b * MMH * 64 + lane;
    const double2* D3 = g_D3 + (size_t)b * MMH * 64 + lane;
    const double2* D4 = g_D4 + (size_t)b * MMH * 64 + lane;
    const double2* D5 = g_D5 + (size_t)b * MMH * 64 + lane;
    const int NWC = (MqA + W - 1) / W;
    PIPE(D1, D2, D3, D4, D5, STEPSA, NWC);
    for (int mI = lane; mI < MqA; mI += 64) msum += g_mmA[b * MMH + mI];
    for (int off = 32; off; off >>= 1) msum += __shfl_xor(msum, off, 64);
  } else {
    // ---------------- beta: diag smax -> s_mid ----------------
    const int aL = Ub >> 1;
    A = (!(Ub & 1) && lane == aL) ? 1.0 : 0.0;
    Bc = ((Ub & 1) && lane == aL) ? 1.0 : 0.0;
    const double2* E1 = g_E1 + (size_t)b * MMH * 64 + lane;
    const double2* E2 = g_E2 + (size_t)b * MMH * 64 + lane;
    const double2* E3 = g_E3 + (size_t)b * MMH * 64 + lane;
    const double2* E4 = g_E4 + (size_t)b * MMH * 64 + lane;
    const double2* E5 = g_E5 + (size_t)b * MMH * 64 + lane;
    const int NWC = (MqB + W - 1) / W;
    PIPE(E1, E2, E3, E4, E5, STEPSB, NWC);
    for (int j = 0; j < remB; ++j) {    // tail raw beta steps
      double2 L1 = g_LB1[j][b * 64 + lane];   // {x, z}
      double2 L2 = g_LB2[j][b * 64 + lane];   // {y, w}
      double shlA = wave_shl1_f64(A);
      double na = fma(A, L1.x, Bc * L1.y);
      double nb = fma(Bc, L2.x, shlA * L2.y);
      A = na; Bc = nb;
    }
    for (int mI = lane; mI < MqB; mI += 64) msum += g_mmB[b * MMH + mI];
    for (int off = 32; off; off >>= 1) msum += __shfl_xor(msum, off, 64);
    for (int j = 0; j < remB; ++j) msum += g_lastmB[b][j];
  }

  // ---------------- pair combine (one add per BLOCK, broadcast) -----------
  g_half[side][b][lane] = make_double2(A, Bc);
  if (lane == 0) g_hms[side][b] = msum;
  int old = 0;
  if (lane == 0)
    old = __hip_atomic_fetch_add(&g_pair[b], 1, __ATOMIC_ACQ_REL,
                                 __HIP_MEMORY_SCOPE_AGENT);
  old = __shfl(old, 0, 64);            // broadcast to the whole wave
  if (old == 1) {                      // second-arriving BLOCK combines
    const int p = 1 - side;
    double2 ps = g_half[p][b][lane];
    float pm = g_hms[p][b];
    double dot = A * ps.x + Bc * ps.y;
    for (int off = 32; off; off >>= 1) dot += __shfl_xor(dot, off, 64);
    int ev = ((__double2hiint(dot) >> 20) & 0x7ff) - 1023;
    double mant = ldexp(dot, -ev);
    float lg2 = (float)ev + flog2((float)mant) + msum + pm;
    if (lane == 0) {
      __hip_atomic_store(&g_pair[b], 0, __ATOMIC_RELAXED, __HIP_MEMORY_SCOPE_AGENT);
      __hip_atomic_store(&g_ps[b], lg2, __ATOMIC_RELEASE, __HIP_MEMORY_SCOPE_AGENT);
      int o2 = __hip_atomic_fetch_add(&g_ctr, 1, __ATOMIC_ACQ_REL,
                                      __HIP_MEMORY_SCOPE_AGENT);
      if (o2 == B - 1) {
        float s = 0.0f;
        for (int i = 0; i < B; ++i)
          s += __hip_atomic_load(&g_ps[i], __ATOMIC_ACQUIRE, __HIP_MEMORY_SCOPE_AGENT);
        out[0] = -s * (LN2 / B);
        __hip_atomic_store(&g_ctr, 0, __ATOMIC_RELAXED, __HIP_MEMORY_SCOPE_AGENT);
      }
    }
  }
#undef LOADG
#undef PIPE
#undef STEPSA
#undef STEPSB
}

extern "C" void kernel_launch(void* const* d_in, const int* in_sizes, int n_in,
                              void* d_out, int out_size, void* d_ws, size_t ws_size,
                              hipStream_t stream) {
  const float* logits = (const float*)d_in[0];
  const int* labels = (const int*)d_in[1];
  const int* logit_len = (const int*)d_in[2];
  const int* label_len = (const int*)d_in[3];
  float* out = (float*)d_out;

  hipLaunchKernelGGL(gather_kernel, dim3(MMH / 4, B, 2), dim3(256), 0, stream,
                     logits, labels, logit_len, label_len);
  hipLaunchKernelGGL(dp_kernel, dim3(2 * B), dim3(64), 0, stream,
                     logit_len, label_len, out);
}